// Round 5
// baseline (265.606 us; speedup 1.0000x reference)
//
#include <hip/hip_runtime.h>
#include <math.h>

#define FBLK 1024
#define NBINS 2048
#define NREP 4
#define CSH 42
#define QMASK ((1ULL << CSH) - 1ULL)

__device__ __forceinline__ float bce_logits(float x, float t){
    return fmaxf(x, 0.f) - x * t + log1pf(expf(-fabsf(x)));
}
__device__ __forceinline__ float smooth_l1(float x){
    float ax = fabsf(x);
    return ax < 1.f ? 0.5f * x * x : ax - 0.5f;
}

struct SharedBlk {
    float4 sg[16][32];
    float  sarea[16][32];
    int    sl[16][32];
    unsigned long long hist[NREP][NBINS];   // 64 KB
    unsigned long long waveT[16];
    unsigned long long waveOff[17];
    float  wsum[16];
    int    wcnt[16];
    double sh_sel;
    float  sh_map;
    int    sh_K, sh_b1, sh_rem, sh_done;
    unsigned long long sh_aboveQ;
};

// Map phase for one wave's share of one (s,b) slice. NIT = iters/plane,
// ACT = active lanes. Culled GTs have IoU==0 exactly -> semantics preserved.
template<int NIT, int ACT>
__device__ __forceinline__ void map_phase(
    const float* __restrict__ pred, int b, int P, int logW, float stride_f,
    const float4* __restrict__ sgw, const float* __restrict__ sareaw,
    const int* __restrict__ slw, int cnt, int w, int lane,
    float4* v, float& loss, int& pc)
{
    const int Qp16 = (P >> 2) >> 4;     // quads per plane per wave
    loss = 0.f; pc = 0;
    #pragma unroll
    for (int a = 0; a < 3; ++a){
        const float half = 0.5f * (float)(3 + a) * stride_f;
        const float sz = 2.f * half;
        const float area_a = sz * sz;
        #pragma unroll
        for (int it = 0; it < NIT; ++it){
            float4 res = make_float4(-1.f, -1.f, -1.f, -1.f);
            if (ACT == 64 || lane < ACT){
                const int quad = w * Qp16 + it * 64 + lane;
                const int pix0 = quad << 2;
                const int x0 = pix0 & ((1 << logW) - 1);
                const int y  = pix0 >> logW;
                const float cy = ((float)y + 0.5f) * stride_f;
                const float Ay = cy - half, Ay2 = cy + half;
                float ax[4], az[4];
                #pragma unroll
                for (int j = 0; j < 4; ++j){
                    float cx = ((float)(x0 + j) + 0.5f) * stride_f;
                    ax[j] = cx - half; az[j] = cx + half;
                }
                float bi[4] = {-1.f,-1.f,-1.f,-1.f};
                float bd[4] = { 1.f, 1.f, 1.f, 1.f};
                int   bg[4] = {0,0,0,0};
                for (int g = 0; g < cnt; ++g){        // wave-uniform bound
                    const float4 G = sgw[g];
                    const float sab = area_a + sareaw[g];
                    const float h = fmaxf(fminf(Ay2, G.w) - fmaxf(Ay, G.y), 0.f);
                    #pragma unroll
                    for (int j = 0; j < 4; ++j){
                        float wdt = fmaxf(fminf(az[j], G.z) - fmaxf(ax[j], G.x), 0.f);
                        float inter = wdt * h;
                        float d = (sab - inter) + 1e-9f;
                        if (inter * bd[j] > bi[j] * d){ bi[j] = inter; bd[j] = d; bg[j] = g; }
                    }
                }
                const size_t cP = (size_t)P;
                const float* pp = pred + ((size_t)b * 24 + (size_t)a * 8) * cP + (size_t)pix0;
                const float4 p4v = *(const float4*)(pp + 4 * cP);
                const float p4a[4] = {p4v.x, p4v.y, p4v.z, p4v.w};
                float vout[4];
                #pragma unroll
                for (int j = 0; j < 4; ++j){
                    const bool pos = 2.f * bi[j] >= bd[j];   // iou >= 0.5
                    const bool neg = bi[j] < 0.4f * bd[j];   // iou <  0.4
                    vout[j] = neg ? bce_logits(p4a[j], 0.f) : -1.f;
                    if (pos){
                        pc++;
                        const float4 G = sgw[bg[j]];
                        float axc = (ax[j] + az[j]) * 0.5f, ayc = (Ay + Ay2) * 0.5f;
                        float aw = fmaxf(az[j] - ax[j], 1e-6f), ah = fmaxf(Ay2 - Ay, 1e-6f);
                        float gxc = (G.x + G.z) * 0.5f, gyc = (G.y + G.w) * 0.5f;
                        float gw = fmaxf(G.z - G.x, 1e-6f), gh = fmaxf(G.w - G.y, 1e-6f);
                        float p0 = pp[0 * cP + j];
                        float p1 = pp[1 * cP + j];
                        float p2 = pp[2 * cP + j];
                        float p3 = pp[3 * cP + j];
                        loss += smooth_l1(p0 - (gxc - axc) / aw);
                        loss += smooth_l1(p1 - (gyc - ayc) / ah);
                        loss += smooth_l1(p2 - logf(gw / aw));
                        loss += smooth_l1(p3 - logf(gh / ah));
                        loss += bce_logits(p4a[j], 1.f);
                        float c0 = pp[5 * cP + j];
                        float c1 = pp[6 * cP + j];
                        float c2 = pp[7 * cP + j];
                        float m = fmaxf(c0, fmaxf(c1, c2));
                        float lse = m + logf(expf(c0 - m) + expf(c1 - m) + expf(c2 - m));
                        int tg = slw[bg[j]];
                        float ct = (tg == 0) ? c0 : ((tg == 1) ? c1 : c2);
                        loss += lse - ct;
                    }
                }
                res = make_float4(vout[0], vout[1], vout[2], vout[3]);
            }
            v[a * NIT + it] = res;
        }
    }
}

__device__ __forceinline__ void bin_val(float vv, int round, int b1,
                                        unsigned long long* histrep)
{
    if (!(vv >= 0.f)) return;
    float t = vv * 256.f;                       // exact (pow2)
    int bin0 = min((int)t, NBINS - 1);
    int key;
    if (round == 0) key = bin0;
    else {
        if (bin0 != b1) return;
        float frac = t - (float)bin0;           // exact
        key = min((int)(frac * 2048.f), NBINS - 1);
    }
    unsigned long long p = (1ULL << CSH) |
        (unsigned long long)(unsigned)(int)(vv * 4194304.f);  // v*2^22
    atomicAdd(&histrep[key], p);
}

// One block per (scale,image): map (values stay in registers) + 2-round
// histogram top-K-sum select + last-ticket finalize.
__global__ __launch_bounds__(FBLK, 4)
void det_fused(const float* __restrict__ p0, const float* __restrict__ p1,
               const float* __restrict__ p2,
               const float* __restrict__ gtb, const int* __restrict__ gtl,
               double* __restrict__ accum, unsigned* __restrict__ done_cnt,
               float* __restrict__ out, int B)
{
    __shared__ SharedBlk S;
    const int sb = blockIdx.x;
    const int s = sb / B, b = sb - s * B;
    const int tid = threadIdx.x, lane = tid & 63, w = tid >> 6;

    const float* pred = (s == 0) ? p0 : (s == 1) ? p1 : p2;
    const int P       = (s == 0) ? 16384 : (s == 1) ? 4096 : 1024;
    const int logW    = (s == 0) ? 7 : (s == 1) ? 6 : 5;
    const float stf   = (s == 0) ? 8.f : (s == 1) ? 16.f : 32.f;

    // per-wave GT y-cull (band = this wave's rows, max anchor half-size)
    const int H = P >> logW;
    const int rpw = H >> 4;                       // rows per wave
    const float half_max = 2.5f * stf;
    const float ymin = ((float)(w * rpw) + 0.5f) * stf - half_max;
    const float ymax = ((float)(w * rpw + rpw - 1) + 0.5f) * stf + half_max;
    int cnt;
    {
        bool keep = false; float4 G;
        if (lane < 32){
            G = ((const float4*)gtb)[b * 32 + lane];
            keep = (G.y < ymax) && (G.w > ymin);
        }
        unsigned long long m = __ballot(keep);
        if (keep){
            int idx = (int)__popcll(m & ((1ULL << lane) - 1ULL));
            S.sg[w][idx] = G;
            S.sarea[w][idx] = (G.z - G.x) * (G.w - G.y);
            S.sl[w][idx] = gtl[b * 32 + lane];
        }
        cnt = (int)__popcll(m);                   // wave-uniform
    }
    // wave-local LDS write->read: no block barrier needed

    float4 v[12];
    #pragma unroll
    for (int k = 0; k < 12; ++k) v[k] = make_float4(-1.f,-1.f,-1.f,-1.f);
    float mloss; int pc;
    if (s == 0)      map_phase<4,64>(pred,b,P,logW,stf,S.sg[w],S.sarea[w],S.sl[w],cnt,w,lane,v,mloss,pc);
    else if (s == 1) map_phase<1,64>(pred,b,P,logW,stf,S.sg[w],S.sarea[w],S.sl[w],cnt,w,lane,v,mloss,pc);
    else             map_phase<1,16>(pred,b,P,logW,stf,S.sg[w],S.sarea[w],S.sl[w],cnt,w,lane,v,mloss,pc);

    // zero hist + reduce map loss/pos-count, one barrier
    for (int i = tid; i < NREP * NBINS; i += FBLK)
        ((unsigned long long*)S.hist)[i] = 0ULL;
    for (int off = 32; off > 0; off >>= 1){
        mloss += __shfl_down(mloss, off);
        pc    += __shfl_down(pc, off);
    }
    if (lane == 0){ S.wsum[w] = mloss; S.wcnt[w] = pc; }
    __syncthreads();
    if (tid == 0){
        float Ls = 0.f; int C = 0;
        for (int i = 0; i < 16; ++i){ Ls += S.wsum[i]; C += S.wcnt[i]; }
        S.sh_map = Ls; S.sh_K = 3 * max(1, C);
        S.sh_done = 0; S.sh_sel = 0.0;
    }
    __syncthreads();

    unsigned long long* histrep = S.hist[w & (NREP - 1)];

    // ---------- round 0 ----------
    #pragma unroll
    for (int k = 0; k < 12; ++k){
        bin_val(v[k].x, 0, 0, histrep);
        bin_val(v[k].y, 0, 0, histrep);
        bin_val(v[k].z, 0, 0, histrep);
        bin_val(v[k].w, 0, 0, histrep);
    }
    __syncthreads();

    const int bhi = NBINS - 1 - 2 * tid;
    {
        unsigned long long c0p = 0ULL, c1p = 0ULL;
        #pragma unroll
        for (int r = 0; r < NREP; ++r){ c0p += S.hist[r][bhi]; c1p += S.hist[r][bhi - 1]; }
        const unsigned long long pair = c0p + c1p;
        unsigned long long ci = pair;
        #pragma unroll
        for (int off = 1; off < 64; off <<= 1){
            unsigned long long cu = __shfl_up(ci, off);
            if (lane >= off) ci += cu;
        }
        if (lane == 63) S.waveT[w] = ci;
        __syncthreads();
        if (tid == 0){
            unsigned long long acc = 0ULL;
            #pragma unroll
            for (int i = 0; i < 16; ++i){ S.waveOff[i] = acc; acc += S.waveT[i]; }
            S.waveOff[16] = acc;
            if (S.sh_K >= (int)(acc >> CSH)){     // keep all negatives
                S.sh_done = 1;
                S.sh_sel = (double)(acc & QMASK) * (1.0 / 4194304.0);
            }
        }
        __syncthreads();
        if (!S.sh_done){
            const int rem = S.sh_K;
            const unsigned long long giP = S.waveOff[w] + ci;
            const unsigned long long geP = giP - pair;
            const int gi = (int)(giP >> CSH);
            const int ge = (int)(geP >> CSH);
            if (ge < rem && rem <= gi){
                const int c0 = (int)(c0p >> CSH);
                int bin, aboveC; unsigned long long aboveQ;
                if (ge + c0 >= rem){ bin = bhi;     aboveC = ge;      aboveQ = geP & QMASK; }
                else               { bin = bhi - 1; aboveC = ge + c0; aboveQ = (geP + c0p) & QMASK; }
                S.sh_b1 = bin; S.sh_rem = rem - aboveC; S.sh_aboveQ = aboveQ;
            }
        }
    }
    __syncthreads();

    // ---------- round 1 ----------
    if (!S.sh_done){                              // block-uniform branch
        for (int i = tid; i < NREP * NBINS; i += FBLK)
            ((unsigned long long*)S.hist)[i] = 0ULL;
        __syncthreads();
        const int b1 = S.sh_b1;
        #pragma unroll
        for (int k = 0; k < 12; ++k){
            bin_val(v[k].x, 1, b1, histrep);
            bin_val(v[k].y, 1, b1, histrep);
            bin_val(v[k].z, 1, b1, histrep);
            bin_val(v[k].w, 1, b1, histrep);
        }
        __syncthreads();

        unsigned long long c0p = 0ULL, c1p = 0ULL;
        #pragma unroll
        for (int r = 0; r < NREP; ++r){ c0p += S.hist[r][bhi]; c1p += S.hist[r][bhi - 1]; }
        const unsigned long long pair = c0p + c1p;
        unsigned long long ci = pair;
        #pragma unroll
        for (int off = 1; off < 64; off <<= 1){
            unsigned long long cu = __shfl_up(ci, off);
            if (lane >= off) ci += cu;
        }
        if (lane == 63) S.waveT[w] = ci;
        __syncthreads();
        if (tid == 0){
            unsigned long long acc = 0ULL;
            #pragma unroll
            for (int i = 0; i < 16; ++i){ S.waveOff[i] = acc; acc += S.waveT[i]; }
            S.waveOff[16] = acc;
        }
        __syncthreads();
        const int rem = S.sh_rem;
        const unsigned long long giP = S.waveOff[w] + ci;
        const unsigned long long geP = giP - pair;
        const int gi = (int)(giP >> CSH);
        const int ge = (int)(geP >> CSH);
        if (ge < rem && rem <= gi){
            const int c0 = (int)(c0p >> CSH);
            int bin, aboveC; unsigned long long aboveQ;
            if (ge + c0 >= rem){ bin = bhi;     aboveC = ge;      aboveQ = geP & QMASK; }
            else               { bin = bhi - 1; aboveC = ge + c0; aboveQ = (geP + c0p) & QMASK; }
            const int newRem = rem - aboveC;
            float thresh = (float)S.sh_b1 * (1.f / 256.f) + (float)bin * (1.f / 524288.f);
            S.sh_sel = (double)(S.sh_aboveQ + aboveQ) * (1.0 / 4194304.0)
                     + (double)newRem * (double)thresh;
        }
        __syncthreads();
    }

    // ---------- finalize: one atomic per block + last-ticket output ----------
    if (tid == 0){
        atomicAdd(accum, (double)S.sh_map + S.sh_sel);
        __threadfence();
        unsigned t = atomicAdd(done_cnt, 1u);
        if (t == (unsigned)(3 * B - 1)){
            __threadfence();
            double tot = atomicAdd(accum, 0.0);
            out[0] = (float)(tot / (double)B);
        }
    }
}

extern "C" void kernel_launch(void* const* d_in, const int* in_sizes, int n_in,
                              void* d_out, int out_size, void* d_ws, size_t ws_size,
                              hipStream_t stream)
{
    const float* gtb = (const float*)d_in[6];
    const int*   gtl = (const int*)d_in[7];
    const int B = in_sizes[6] / (32 * 4);   // 64

    double*   accum = (double*)d_ws;
    unsigned* done  = (unsigned*)((char*)d_ws + 8);

    hipMemsetAsync(d_ws, 0, 16, stream);

    det_fused<<<dim3(3 * B), FBLK, 0, stream>>>(
        (const float*)d_in[0], (const float*)d_in[2], (const float*)d_in[4],
        gtb, gtl, accum, done, (float*)d_out, B);
}